// Round 5
// baseline (147.767 us; speedup 1.0000x reference)
//
#include <hip/hip_runtime.h>
#include <hip/hip_fp16.h>

#define HH 512
#define WW 512
#define BB 8
#define HW (HH * WW)
#define DXS 0.5f
#define NSTEPS 8

typedef float f2  __attribute__((ext_vector_type(2)));
typedef float f4a __attribute__((ext_vector_type(4)));
typedef unsigned int u2u __attribute__((ext_vector_type(2), aligned(4)));
typedef unsigned int u4a __attribute__((ext_vector_type(4)));

__device__ __forceinline__ f2 h2f(unsigned int h) {
    __half2 v = __builtin_bit_cast(__half2, h);
    float2 f = __half22float2(v);
    return (f2){f.x, f.y};
}

__device__ __forceinline__ unsigned int f2h(float a, float b) {
    __half2 h = __floats2half2_rn(a, b);
    return __builtin_bit_cast(unsigned int, h);
}

// ---------------- pack prepass: (B,2,H,W) f32 -> (B,H,W) half2 ----------------
__global__ __launch_bounds__(256) void pack_half_kernel(const float* __restrict__ vf_true,
                                                        const float* __restrict__ vf_pred,
                                                        unsigned int* __restrict__ tpack,
                                                        unsigned int* __restrict__ ppack) {
    int b     = blockIdx.x & 7;                   // XCD-batch affinity
    int chunk = blockIdx.x >> 3;                  // 0..255
    int i     = chunk * 256 + threadIdx.x;        // 4-px group within batch
    int pix   = i * 4;

    const float* t = vf_true + (size_t)b * 2 * HW;
    const float* p = vf_pred + (size_t)b * 2 * HW;

    f4a tx = *(const f4a*)(t + pix);
    f4a ty = *(const f4a*)(t + pix + HW);
    f4a px = *(const f4a*)(p + pix);
    f4a py = *(const f4a*)(p + pix + HW);

    u4a ot = { f2h(tx.x, ty.x), f2h(tx.y, ty.y), f2h(tx.z, ty.z), f2h(tx.w, ty.w) };
    u4a op = { f2h(px.x, py.x), f2h(px.y, py.y), f2h(px.z, py.z), f2h(px.w, py.w) };

    *(u4a*)(tpack + (size_t)b * HW + pix) = ot;
    *(u4a*)(ppack + (size_t)b * HW + pix) = op;
}

// ---------------- bilinear on half2 field: 2 x dwordx2 per sample ----------------
__device__ __forceinline__ f2 bilinh(const unsigned int* __restrict__ f,
                                     float px, float py) {
    float x = fminf(fmaxf(px, 0.0f), (float)(WW - 1));
    float y = fminf(fmaxf(py, 0.0f), (float)(HH - 1));
    float x0f = fminf(floorf(x), (float)(WW - 2));
    float y0f = fminf(floorf(y), (float)(HH - 2));
    float wx = x - x0f;
    float wy = y - y0f;
    int idx = (int)fmaf(y0f, (float)WW, x0f);     // exact: < 2^24
    u2u r0 = *(const u2u*)(f + idx);
    u2u r1 = *(const u2u*)(f + idx + WW);
    f2 v00 = h2f(r0.x), v01 = h2f(r0.y);
    f2 v10 = h2f(r1.x), v11 = h2f(r1.y);
    f2 top = v00 + wx * (v01 - v00);
    f2 bot = v10 + wx * (v11 - v10);
    return top + wy * (bot - top);
}

__global__ __launch_bounds__(256) void ivp_loss_half(const unsigned int* __restrict__ tpack,
                                                     const unsigned int* __restrict__ ppack,
                                                     double* __restrict__ acc,
                                                     unsigned int* __restrict__ cnt,
                                                     float* __restrict__ out) {
    int b   = blockIdx.x & 7;          // XCD-batch affinity
    int row = blockIdx.x >> 3;         // 0..511
    int tid = threadIdx.x;

    const unsigned int* t = tpack + (size_t)b * HW;
    const unsigned int* p = ppack + (size_t)b * HW;

    int pix0 = row * WW + tid;
    int pix1 = pix0 + 256;

    // step 0: positions are the exact integer grid -> bilinear == direct
    // field read (coalesced 4B loads, no gather)
    f2 vt0 = h2f(t[pix0]);
    f2 vp0 = h2f(p[pix0]);
    f2 vt1 = h2f(t[pix1]);
    f2 vp1 = h2f(p[pix1]);

    float xa = (float)tid, xb = (float)(tid + 256), yy = (float)row;

    float ptx0 = fmaf(DXS, vt0.x, xa), pty0 = fmaf(DXS, vt0.y, yy);
    float ppx0 = fmaf(DXS, vp0.x, xa), ppy0 = fmaf(DXS, vp0.y, yy);
    float ptx1 = fmaf(DXS, vt1.x, xb), pty1 = fmaf(DXS, vt1.y, yy);
    float ppx1 = fmaf(DXS, vp1.x, xb), ppy1 = fmaf(DXS, vp1.y, yy);

    float dx0 = ptx0 - ppx0, dy0 = pty0 - ppy0;
    float dx1 = ptx1 - ppx1, dy1 = pty1 - ppy1;
    float sum = dx0 * dx0 + dy0 * dy0 + dx1 * dx1 + dy1 * dy1;

    #pragma unroll
    for (int s = 1; s < NSTEPS; ++s) {
        f2 a = bilinh(t, ptx0, pty0);
        f2 b2 = bilinh(p, ppx0, ppy0);
        f2 c = bilinh(t, ptx1, pty1);
        f2 d = bilinh(p, ppx1, ppy1);
        ptx0 += DXS * a.x;   pty0 += DXS * a.y;
        ppx0 += DXS * b2.x;  ppy0 += DXS * b2.y;
        ptx1 += DXS * c.x;   pty1 += DXS * c.y;
        ppx1 += DXS * d.x;   ppy1 += DXS * d.y;
        float ex0 = ptx0 - ppx0, ey0 = pty0 - ppy0;
        float ex1 = ptx1 - ppx1, ey1 = pty1 - ppy1;
        sum += ex0 * ex0 + ey0 * ey0;
        sum += ex1 * ex1 + ey1 * ey1;
    }

    // wave reduce (64 lanes)
    for (int off = 32; off > 0; off >>= 1)
        sum += __shfl_down(sum, off, 64);

    __shared__ float wsum[4];
    int lane = threadIdx.x & 63;
    int wave = threadIdx.x >> 6;
    if (lane == 0) wsum[wave] = sum;
    __syncthreads();
    if (threadIdx.x == 0) {
        double blocksum = (double)wsum[0] + (double)wsum[1]
                        + (double)wsum[2] + (double)wsum[3];
        atomicAdd(acc, blocksum);
        __threadfence();
        unsigned int done = atomicAdd(cnt, 1u);
        if (done == gridDim.x - 1) {
            double total = atomicAdd(acc, 0.0);   // atomic read-back, device scope
            const double n = (double)(NSTEPS + 1) * BB * 2 * HW;
            out[0] = (float)(total / n);
        }
    }
}

// ---------------- fallback (no workspace): f32 unpacked ----------------
__device__ __forceinline__ void bilinear(const float* __restrict__ c0,
                                         const float* __restrict__ c1,
                                         float px, float py,
                                         float& vx, float& vy) {
    float x = fminf(fmaxf(px, 0.0f), (float)(WW - 1));
    float y = fminf(fmaxf(py, 0.0f), (float)(HH - 1));
    float x0f = fminf(floorf(x), (float)(WW - 2));
    float y0f = fminf(floorf(y), (float)(HH - 2));
    float wx = x - x0f;
    float wy = y - y0f;
    int i00 = (int)fmaf(y0f, (float)WW, x0f);
    float w00 = (1.0f - wx) * (1.0f - wy);
    float w01 = wx * (1.0f - wy);
    float w10 = (1.0f - wx) * wy;
    float w11 = wx * wy;
    vx = c0[i00] * w00 + c0[i00 + 1] * w01 + c0[i00 + WW] * w10 + c0[i00 + WW + 1] * w11;
    vy = c1[i00] * w00 + c1[i00 + 1] * w01 + c1[i00 + WW] * w10 + c1[i00 + WW + 1] * w11;
}

__global__ __launch_bounds__(256) void ivp_loss_kernel(const float* __restrict__ vf_pred,
                                                       const float* __restrict__ vf_true,
                                                       double* __restrict__ acc) {
    int b   = blockIdx.x & 7;
    int row = blockIdx.x >> 3;
    int tid = threadIdx.x;

    const float* t0 = vf_true + (size_t)b * 2 * HW;
    const float* t1 = t0 + HW;
    const float* p0 = vf_pred + (size_t)b * 2 * HW;
    const float* p1 = p0 + HW;

    float ptx0 = (float)tid,         pty0 = (float)row;
    float ppx0 = ptx0,               ppy0 = pty0;
    float ptx1 = (float)(tid + 256), pty1 = (float)row;
    float ppx1 = ptx1,               ppy1 = pty1;

    float sum = 0.0f;

    #pragma unroll
    for (int s = 0; s < NSTEPS; ++s) {
        float vtx0, vty0, vpx0, vpy0;
        float vtx1, vty1, vpx1, vpy1;
        bilinear(t0, t1, ptx0, pty0, vtx0, vty0);
        bilinear(p0, p1, ppx0, ppy0, vpx0, vpy0);
        bilinear(t0, t1, ptx1, pty1, vtx1, vty1);
        bilinear(p0, p1, ppx1, ppy1, vpx1, vpy1);
        ptx0 += DXS * vtx0;  pty0 += DXS * vty0;
        ppx0 += DXS * vpx0;  ppy0 += DXS * vpy0;
        ptx1 += DXS * vtx1;  pty1 += DXS * vty1;
        ppx1 += DXS * vpx1;  ppy1 += DXS * vpy1;
        float dx0 = ptx0 - ppx0, dy0 = pty0 - ppy0;
        float dx1 = ptx1 - ppx1, dy1 = pty1 - ppy1;
        sum += dx0 * dx0 + dy0 * dy0;
        sum += dx1 * dx1 + dy1 * dy1;
    }

    for (int off = 32; off > 0; off >>= 1)
        sum += __shfl_down(sum, off, 64);

    __shared__ float wsum[4];
    int lane = threadIdx.x & 63;
    int wave = threadIdx.x >> 6;
    if (lane == 0) wsum[wave] = sum;
    __syncthreads();
    if (threadIdx.x == 0) {
        double blocksum = (double)wsum[0] + (double)wsum[1]
                        + (double)wsum[2] + (double)wsum[3];
        atomicAdd(acc, blocksum);
    }
}

__global__ void ivp_finalize_kernel(const double* __restrict__ acc,
                                    float* __restrict__ out) {
    const double total = (double)(NSTEPS + 1) * BB * 2 * HW;
    out[0] = (float)(acc[0] / total);
}

extern "C" void kernel_launch(void* const* d_in, const int* in_sizes, int n_in,
                              void* d_out, int out_size, void* d_ws, size_t ws_size,
                              hipStream_t stream) {
    const float* vf_pred = (const float*)d_in[0];
    const float* vf_true = (const float*)d_in[1];
    float* out = (float*)d_out;

    const size_t pack_bytes = (size_t)BB * HW * sizeof(unsigned int);  // 8 MB per field
    const size_t need = 256 + 2 * pack_bytes;

    double* acc = (double*)d_ws;
    unsigned int* cnt = (unsigned int*)((char*)d_ws + 8);
    hipMemsetAsync(d_ws, 0, 16, stream);

    if (ws_size >= need) {
        unsigned int* tpack = (unsigned int*)((char*)d_ws + 256);
        unsigned int* ppack = (unsigned int*)((char*)d_ws + 256 + pack_bytes);
        pack_half_kernel<<<BB * HW / 4 / 256, 256, 0, stream>>>(vf_true, vf_pred, tpack, ppack);
        ivp_loss_half<<<BB * HH, 256, 0, stream>>>(tpack, ppack, acc, cnt, out);
    } else {
        ivp_loss_kernel<<<BB * HH, 256, 0, stream>>>(vf_pred, vf_true, acc);
        ivp_finalize_kernel<<<1, 1, 0, stream>>>(acc, out);
    }
}

// Round 6
// 80.877 us; speedup vs baseline: 1.8271x; 1.8271x over previous
//
#include <hip/hip_runtime.h>

#define HH 512
#define WW 512
#define BB 8
#define HW (HH * WW)
#define DXS 0.5f
#define NSTEPS 8

// 16B vector with 8B alignment (corner-pair loads are only 8B-aligned)
typedef float f4u __attribute__((ext_vector_type(4), aligned(8)));
typedef float f4a __attribute__((ext_vector_type(4)));

// ---------------- pack prepass: (B,2,H,W) -> (B,H,SW,2), padded stride ----------------
// XCD-batch affinity: blk%8 == batch, so batch b's packed lines live in XCD b's L2.
template<int SW>
__global__ __launch_bounds__(256) void pack_kernel(const float* __restrict__ vf_true,
                                                   const float* __restrict__ vf_pred,
                                                   float2* __restrict__ tpack,
                                                   float2* __restrict__ ppack) {
    int b  = blockIdx.x & 7;
    int pr = blockIdx.x >> 3;           // 0..255 (row pair)
    int rl = threadIdx.x >> 7;          // 0..1
    int g  = threadIdx.x & 127;         // 4-px group in row
    int row = pr * 2 + rl;
    int pix = row * WW + g * 4;

    const float* t = vf_true + (size_t)b * 2 * HW;
    const float* p = vf_pred + (size_t)b * 2 * HW;

    f4a tx = *(const f4a*)(t + pix);
    f4a ty = *(const f4a*)(t + pix + HW);
    f4a px = *(const f4a*)(p + pix);
    f4a py = *(const f4a*)(p + pix + HW);

    size_t o = (size_t)b * HH * SW + (size_t)row * SW + g * 4;
    f4a* ot = (f4a*)(tpack + o);
    f4a* op = (f4a*)(ppack + o);
    ot[0] = (f4a){tx.x, ty.x, tx.y, ty.y};
    ot[1] = (f4a){tx.z, ty.z, tx.w, ty.w};
    op[0] = (f4a){px.x, py.x, px.y, py.y};
    op[1] = (f4a){px.z, py.z, px.w, py.w};
}

// ---------------- bilinear: 2 x 16B loads per sample ----------------
template<int SW>
__device__ __forceinline__ void bilin4(const float2* __restrict__ f,
                                       float px, float py,
                                       float& vx, float& vy) {
    float x = fminf(fmaxf(px, 0.0f), (float)(WW - 1));
    float y = fminf(fmaxf(py, 0.0f), (float)(HH - 1));
    float x0f = fminf(floorf(x), (float)(WW - 2));
    float y0f = fminf(floorf(y), (float)(HH - 2));
    float wx = x - x0f;
    float wy = y - y0f;
    int idx = (int)fmaf(y0f, (float)SW, x0f);     // exact: < 2^24
    const f4u* r0 = (const f4u*)(f + idx);
    const f4u* r1 = (const f4u*)(f + idx + SW);
    f4u a = *r0;   // v00.x v00.y v01.x v01.y
    f4u c = *r1;   // v10.x v10.y v11.x v11.y
    float ax = a.x + wx * (a.z - a.x);
    float ay = a.y + wx * (a.w - a.y);
    float cx = c.x + wx * (c.z - c.x);
    float cy = c.y + wx * (c.w - c.y);
    vx = ax + wy * (cx - ax);
    vy = ay + wy * (cy - ay);
}

template<int SW>
__global__ __launch_bounds__(256) void ivp_loss_packed(const float2* __restrict__ tpack,
                                                       const float2* __restrict__ ppack,
                                                       double* __restrict__ acc) {
    int b   = blockIdx.x & 7;          // XCD-batch affinity
    int row = blockIdx.x >> 3;         // 0..511
    int tid = threadIdx.x;

    const float2* t = tpack + (size_t)b * HH * SW;
    const float2* p = ppack + (size_t)b * HH * SW;

    int pix0 = row * SW + tid;
    int pix1 = pix0 + 256;

    // step 0: positions are the exact integer grid -> direct coalesced reads
    float2 vt0 = t[pix0];
    float2 vp0 = p[pix0];
    float2 vt1 = t[pix1];
    float2 vp1 = p[pix1];

    float xa = (float)tid, xb = (float)(tid + 256), yy = (float)row;

    float ptx0 = fmaf(DXS, vt0.x, xa), pty0 = fmaf(DXS, vt0.y, yy);
    float ppx0 = fmaf(DXS, vp0.x, xa), ppy0 = fmaf(DXS, vp0.y, yy);
    float ptx1 = fmaf(DXS, vt1.x, xb), pty1 = fmaf(DXS, vt1.y, yy);
    float ppx1 = fmaf(DXS, vp1.x, xb), ppy1 = fmaf(DXS, vp1.y, yy);

    float dx0 = ptx0 - ppx0, dy0 = pty0 - ppy0;
    float dx1 = ptx1 - ppx1, dy1 = pty1 - ppy1;
    float sum = dx0 * dx0 + dy0 * dy0 + dx1 * dx1 + dy1 * dy1;

    #pragma unroll
    for (int s = 1; s < NSTEPS; ++s) {
        float vtx0, vty0, vpx0, vpy0;
        float vtx1, vty1, vpx1, vpy1;
        bilin4<SW>(t, ptx0, pty0, vtx0, vty0);
        bilin4<SW>(p, ppx0, ppy0, vpx0, vpy0);
        bilin4<SW>(t, ptx1, pty1, vtx1, vty1);
        bilin4<SW>(p, ppx1, ppy1, vpx1, vpy1);
        ptx0 += DXS * vtx0;  pty0 += DXS * vty0;
        ppx0 += DXS * vpx0;  ppy0 += DXS * vpy0;
        ptx1 += DXS * vtx1;  pty1 += DXS * vty1;
        ppx1 += DXS * vpx1;  ppy1 += DXS * vpy1;
        float ex0 = ptx0 - ppx0, ey0 = pty0 - ppy0;
        float ex1 = ptx1 - ppx1, ey1 = pty1 - ppy1;
        sum += ex0 * ex0 + ey0 * ey0;
        sum += ex1 * ex1 + ey1 * ey1;
    }

    for (int off = 32; off > 0; off >>= 1)
        sum += __shfl_down(sum, off, 64);

    __shared__ float wsum[4];
    int lane = threadIdx.x & 63;
    int wave = threadIdx.x >> 6;
    if (lane == 0) wsum[wave] = sum;
    __syncthreads();
    if (threadIdx.x == 0) {
        double blocksum = (double)wsum[0] + (double)wsum[1]
                        + (double)wsum[2] + (double)wsum[3];
        atomicAdd(acc, blocksum);
    }
}

// ---------------- fallback (no workspace): f32 unpacked ----------------
__device__ __forceinline__ void bilinear(const float* __restrict__ c0,
                                         const float* __restrict__ c1,
                                         float px, float py,
                                         float& vx, float& vy) {
    float x = fminf(fmaxf(px, 0.0f), (float)(WW - 1));
    float y = fminf(fmaxf(py, 0.0f), (float)(HH - 1));
    float x0f = fminf(floorf(x), (float)(WW - 2));
    float y0f = fminf(floorf(y), (float)(HH - 2));
    float wx = x - x0f;
    float wy = y - y0f;
    int i00 = (int)fmaf(y0f, (float)WW, x0f);
    float w00 = (1.0f - wx) * (1.0f - wy);
    float w01 = wx * (1.0f - wy);
    float w10 = (1.0f - wx) * wy;
    float w11 = wx * wy;
    vx = c0[i00] * w00 + c0[i00 + 1] * w01 + c0[i00 + WW] * w10 + c0[i00 + WW + 1] * w11;
    vy = c1[i00] * w00 + c1[i00 + 1] * w01 + c1[i00 + WW] * w10 + c1[i00 + WW + 1] * w11;
}

__global__ __launch_bounds__(256) void ivp_loss_kernel(const float* __restrict__ vf_pred,
                                                       const float* __restrict__ vf_true,
                                                       double* __restrict__ acc) {
    int b   = blockIdx.x & 7;
    int row = blockIdx.x >> 3;
    int tid = threadIdx.x;

    const float* t0 = vf_true + (size_t)b * 2 * HW;
    const float* t1 = t0 + HW;
    const float* p0 = vf_pred + (size_t)b * 2 * HW;
    const float* p1 = p0 + HW;

    float ptx0 = (float)tid,         pty0 = (float)row;
    float ppx0 = ptx0,               ppy0 = pty0;
    float ptx1 = (float)(tid + 256), pty1 = (float)row;
    float ppx1 = ptx1,               ppy1 = pty1;

    float sum = 0.0f;

    #pragma unroll
    for (int s = 0; s < NSTEPS; ++s) {
        float vtx0, vty0, vpx0, vpy0;
        float vtx1, vty1, vpx1, vpy1;
        bilinear(t0, t1, ptx0, pty0, vtx0, vty0);
        bilinear(p0, p1, ppx0, ppy0, vpx0, vpy0);
        bilinear(t0, t1, ptx1, pty1, vtx1, vty1);
        bilinear(p0, p1, ppx1, ppy1, vpx1, vpy1);
        ptx0 += DXS * vtx0;  pty0 += DXS * vty0;
        ppx0 += DXS * vpx0;  ppy0 += DXS * vpy0;
        ptx1 += DXS * vtx1;  pty1 += DXS * vty1;
        ppx1 += DXS * vpx1;  ppy1 += DXS * vpy1;
        float dx0 = ptx0 - ppx0, dy0 = pty0 - ppy0;
        float dx1 = ptx1 - ppx1, dy1 = pty1 - ppy1;
        sum += dx0 * dx0 + dy0 * dy0;
        sum += dx1 * dx1 + dy1 * dy1;
    }

    for (int off = 32; off > 0; off >>= 1)
        sum += __shfl_down(sum, off, 64);

    __shared__ float wsum[4];
    int lane = threadIdx.x & 63;
    int wave = threadIdx.x >> 6;
    if (lane == 0) wsum[wave] = sum;
    __syncthreads();
    if (threadIdx.x == 0) {
        double blocksum = (double)wsum[0] + (double)wsum[1]
                        + (double)wsum[2] + (double)wsum[3];
        atomicAdd(acc, blocksum);
    }
}

// ---------------- finalize ----------------
__global__ void ivp_finalize_kernel(const double* __restrict__ acc,
                                    float* __restrict__ out) {
    const double total = (double)(NSTEPS + 1) * BB * 2 * HW;
    out[0] = (float)(acc[0] / total);
}

extern "C" void kernel_launch(void* const* d_in, const int* in_sizes, int n_in,
                              void* d_out, int out_size, void* d_ws, size_t ws_size,
                              hipStream_t stream) {
    const float* vf_pred = (const float*)d_in[0];
    const float* vf_true = (const float*)d_in[1];
    float* out = (float*)d_out;

    const size_t pb_pad  = (size_t)BB * HH * 520 * sizeof(float2);  // ~17.0 MB/field
    const size_t pb_lin  = (size_t)BB * HH * 512 * sizeof(float2);  // 16.8 MB/field

    double* acc = (double*)d_ws;
    hipMemsetAsync(d_ws, 0, 16, stream);

    if (ws_size >= 256 + 2 * pb_pad) {
        float2* tpack = (float2*)((char*)d_ws + 256);
        float2* ppack = (float2*)((char*)d_ws + 256 + pb_pad);
        pack_kernel<520><<<BB * HH / 2, 256, 0, stream>>>(vf_true, vf_pred, tpack, ppack);
        ivp_loss_packed<520><<<BB * HH, 256, 0, stream>>>(tpack, ppack, acc);
    } else if (ws_size >= 256 + 2 * pb_lin) {
        float2* tpack = (float2*)((char*)d_ws + 256);
        float2* ppack = (float2*)((char*)d_ws + 256 + pb_lin);
        pack_kernel<512><<<BB * HH / 2, 256, 0, stream>>>(vf_true, vf_pred, tpack, ppack);
        ivp_loss_packed<512><<<BB * HH, 256, 0, stream>>>(tpack, ppack, acc);
    } else {
        ivp_loss_kernel<<<BB * HH, 256, 0, stream>>>(vf_pred, vf_true, acc);
    }
    ivp_finalize_kernel<<<1, 1, 0, stream>>>(acc, out);
}

// Round 7
// 56.003 us; speedup vs baseline: 2.6385x; 1.4442x over previous
//
#include <hip/hip_runtime.h>
#include <hip/hip_fp16.h>

#define HH 512
#define WW 512
#define BB 8
#define HW (HH * WW)
#define DXS 0.5f
#define NSTEPS 8

#define R_BLK 4          // rows of trajectories per block
#define BAND 15          // staged rows per field
#define LSW 520          // LDS row stride in u32 (520%32=8 -> +8 banks/row; *4 %16==0)

typedef float f2  __attribute__((ext_vector_type(2)));
typedef float f4a __attribute__((ext_vector_type(4)));
typedef unsigned int u4a __attribute__((ext_vector_type(4)));

__device__ __forceinline__ f2 h2f(unsigned int h) {
    __half2 v = __builtin_bit_cast(__half2, h);
    float2 f = __half22float2(v);
    return (f2){f.x, f.y};
}
__device__ __forceinline__ unsigned int f2h(float a, float b) {
    __half2 h = __floats2half2_rn(a, b);
    return __builtin_bit_cast(unsigned int, h);
}

// bilinear from LDS half2 band, with rare global-f32 fallback for out-of-band y
__device__ __forceinline__ f2 bilin_lds(const unsigned int* __restrict__ lds,
                                        int band_lo,
                                        const float* __restrict__ g0,
                                        const float* __restrict__ g1,
                                        float px, float py) {
    float x = fminf(fmaxf(px, 0.0f), (float)(WW - 1));
    float y = fminf(fmaxf(py, 0.0f), (float)(HH - 1));
    float x0f = fminf(floorf(x), (float)(WW - 2));
    float y0f = fminf(floorf(y), (float)(HH - 2));
    float wx = x - x0f;
    float wy = y - y0f;
    int xi = (int)x0f;
    int yi = (int)y0f;
    int r = yi - band_lo;
    f2 out;
    if (r >= 0 && r <= BAND - 2) {
        int idx = r * LSW + xi;
        unsigned int a0 = lds[idx];
        unsigned int a1 = lds[idx + 1];
        unsigned int b0 = lds[idx + LSW];
        unsigned int b1 = lds[idx + LSW + 1];
        f2 v00 = h2f(a0), v01 = h2f(a1), v10 = h2f(b0), v11 = h2f(b1);
        f2 top = v00 + wx * (v01 - v00);
        f2 bot = v10 + wx * (v11 - v10);
        out = top + wy * (bot - top);
    } else {
        int i00 = yi * WW + xi;
        float w00 = (1.0f - wx) * (1.0f - wy);
        float w01 = wx * (1.0f - wy);
        float w10 = (1.0f - wx) * wy;
        float w11 = wx * wy;
        out.x = g0[i00] * w00 + g0[i00 + 1] * w01 + g0[i00 + WW] * w10 + g0[i00 + WW + 1] * w11;
        out.y = g1[i00] * w00 + g1[i00 + 1] * w01 + g1[i00 + WW] * w10 + g1[i00 + WW + 1] * w11;
    }
    return out;
}

__global__ __launch_bounds__(256) void ivp_loss_lds(const float* __restrict__ vf_pred,
                                                    const float* __restrict__ vf_true,
                                                    double* __restrict__ acc) {
    __shared__ unsigned int lt[BAND * LSW];   // true field, half2/px
    __shared__ unsigned int lp[BAND * LSW];   // pred field, half2/px
    __shared__ float wsum[4];

    int b    = blockIdx.x & 7;               // XCD-batch affinity
    int rb   = blockIdx.x >> 3;              // 0..127
    int base = rb * R_BLK;
    int band_lo = min(max(base - 5, 0), HH - BAND);

    const float* tg0 = vf_true + (size_t)b * 2 * HW;
    const float* tg1 = tg0 + HW;
    const float* pg0 = vf_pred + (size_t)b * 2 * HW;
    const float* pg1 = pg0 + HW;

    // ---- stage BAND rows of both fields into LDS as half2, coalesced ----
    for (int i = threadIdx.x; i < BAND * 128; i += 256) {
        int rl = i >> 7;                     // 0..14
        int g  = i & 127;                    // 4-px group
        int off = (band_lo + rl) * WW + g * 4;
        f4a tx = *(const f4a*)(tg0 + off);
        f4a ty = *(const f4a*)(tg1 + off);
        f4a px = *(const f4a*)(pg0 + off);
        f4a py = *(const f4a*)(pg1 + off);
        u4a wt = { f2h(tx.x, ty.x), f2h(tx.y, ty.y), f2h(tx.z, ty.z), f2h(tx.w, ty.w) };
        u4a wp = { f2h(px.x, py.x), f2h(px.y, py.y), f2h(px.z, py.z), f2h(px.w, py.w) };
        *(u4a*)&lt[rl * LSW + g * 4] = wt;
        *(u4a*)&lp[rl * LSW + g * 4] = wp;
    }
    __syncthreads();

    // ---- per-thread: 8 trajectory chains (one row per wave, x = lane+64c) ----
    int lane = threadIdx.x & 63;
    int wv   = threadIdx.x >> 6;
    int row  = base + wv;
    float fy = (float)row;

    float ptx[8], pty[8], ppx[8], ppy[8];
    float sum = 0.0f;

    // step 1: positions are the exact integer grid -> direct LDS reads
    #pragma unroll
    for (int c = 0; c < 8; ++c) {
        int x  = lane + 64 * c;
        int li = (row - band_lo) * LSW + x;
        f2 vt = h2f(lt[li]);
        f2 vp = h2f(lp[li]);
        float fx = (float)x;
        ptx[c] = fmaf(DXS, vt.x, fx);  pty[c] = fmaf(DXS, vt.y, fy);
        ppx[c] = fmaf(DXS, vp.x, fx);  ppy[c] = fmaf(DXS, vp.y, fy);
        float dx = ptx[c] - ppx[c], dy = pty[c] - ppy[c];
        sum += dx * dx + dy * dy;
    }

    // steps 2..8: LDS gathers
    #pragma unroll 1
    for (int s = 1; s < NSTEPS; ++s) {
        #pragma unroll
        for (int c = 0; c < 8; ++c) {
            f2 vt = bilin_lds(lt, band_lo, tg0, tg1, ptx[c], pty[c]);
            f2 vp = bilin_lds(lp, band_lo, pg0, pg1, ppx[c], ppy[c]);
            ptx[c] += DXS * vt.x;  pty[c] += DXS * vt.y;
            ppx[c] += DXS * vp.x;  ppy[c] += DXS * vp.y;
            float dx = ptx[c] - ppx[c], dy = pty[c] - ppy[c];
            sum += dx * dx + dy * dy;
        }
    }

    // ---- reduce ----
    for (int off = 32; off > 0; off >>= 1)
        sum += __shfl_down(sum, off, 64);
    if (lane == 0) wsum[wv] = sum;
    __syncthreads();
    if (threadIdx.x == 0) {
        double blocksum = (double)wsum[0] + (double)wsum[1]
                        + (double)wsum[2] + (double)wsum[3];
        atomicAdd(acc, blocksum);
    }
}

__global__ void ivp_finalize_kernel(const double* __restrict__ acc,
                                    float* __restrict__ out) {
    const double total = (double)(NSTEPS + 1) * BB * 2 * HW;
    out[0] = (float)(acc[0] / total);
}

extern "C" void kernel_launch(void* const* d_in, const int* in_sizes, int n_in,
                              void* d_out, int out_size, void* d_ws, size_t ws_size,
                              hipStream_t stream) {
    const float* vf_pred = (const float*)d_in[0];
    const float* vf_true = (const float*)d_in[1];
    float* out = (float*)d_out;
    double* acc = (double*)d_ws;

    hipMemsetAsync(d_ws, 0, 16, stream);

    int blocks = BB * (HH / R_BLK);          // 8 * 128 = 1024
    ivp_loss_lds<<<blocks, 256, 0, stream>>>(vf_pred, vf_true, acc);
    ivp_finalize_kernel<<<1, 1, 0, stream>>>(acc, out);
}